// Round 3
// baseline (364.428 us; speedup 1.0000x reference)
//
#include <hip/hip_runtime.h>
#include <hip/hip_bf16.h>
#include <cstddef>

#define H_   22
#define T_   1000
#define B_   64
#define NSEQ (B_ * H_)      // 1408 sequences (B*C, C==22)
#define KP   22             // conv out channels
#define TP   10             // pooled time positions
#define POOL 100
#define CSTR 488            // conv hl row stride in fp16 (484 -> 488 = 61 uint4)
#define SEG  10             // temporal segments
#define SEGLEN (T_ / SEG)   // 100
#define WARM 32             // warm-up steps (R12-validated: fp16-floor exact)
#define SPW  16             // sequences per wave (MFMA M dimension)
#define NWQ  (NSEQ / SPW)   // 88 wave groups

typedef _Float16 half2_t  __attribute__((ext_vector_type(2)));
typedef _Float16 f16x8_t  __attribute__((ext_vector_type(8)));
typedef float    f32x4_t  __attribute__((ext_vector_type(4)));

#define LOG2E_F 1.44269504088896f

// Guaranteed-single-instruction transcendentals (R2-validated: -30% on lstm_k).
__device__ __forceinline__ float exp2_hw(float x) {
    float r; asm("v_exp_f32 %0, %1" : "=v"(r) : "v"(x)); return r;
}
__device__ __forceinline__ float rcp_hw(float x) {
    float r; asm("v_rcp_f32 %0, %1" : "=v"(r) : "v"(x)); return r;
}
// sigm: mul+exp+add+rcp (4 VALU); correct saturation at +/-inf.
__device__ __forceinline__ float sigm(float x) {
    return rcp_hw(1.f + exp2_hw(-LOG2E_F * x));
}
// tanh: mul+exp+add+rcp+fma (5 VALU); correct saturation.
__device__ __forceinline__ float tanhfast(float x) {
    return fmaf(-2.f, rcp_hw(1.f + exp2_hw((2.f * LOG2E_F) * x)), 1.f);
}

// ---------------------------------------------------------------------------
// Kernel 1 (R17): MFMA-batched independent LSTMs.
// R2 counters: ~199 issued insts per 2-seq step vs ~75 in source (AGPR/remat
// tax, register-budget-invariant across 3 rounds) => the scalar-lane dot
// structure is a dead end. Restructure: 1 wave = 16 sequences; the hh-matvec
// gates[16][88] = h[16][22] @ W_hh^T becomes 8x mfma_f32_16x16x32_f16
// (gates padded per-gate to 32 cols => one gate type per tile => branchless
// activations). x*W_ih+bias rides in as the fp32 C-initializer (precision
// path identical to the fdot2 version: fp16 h/W, fp32 accumulate).
// Fragment layouts (guide-verified):
//   D/C: row = 4*(lane>>4)+reg, col = lane&15          [m89/m91]
//   A:   row = lane&15, k = 4*(lane>>4)+j (elems 0-3), +16 (elems 4-7)
//   B:   col = lane&15, same k mapping                  [m156/m162 tr-read]
// Zero discipline: B rows k>=22 and cols hcol>=22 are zeroed in registers,
// so LDS cols 22..31 (activation dump for invalid positions) contribute 0;
// invalid preacts are exactly 0 => states stay bounded, no NaN path.
// h exchange via per-wave LDS [16][36] fp16 (72B stride: banks 18m+2g%32,
// <=2 lanes/bank => conflict-free); x staged 16 steps/1KB at a time.
// Grid: 88*SEG = 880 single-wave blocks; waves_per_eu(1,2) => 256-reg
// budget (live set ~120: acc 32 + B 32 + wih/bias 16 + c 8 + ptrs/misc).
// ---------------------------------------------------------------------------
__global__ __launch_bounds__(64)
__attribute__((amdgpu_waves_per_eu(1, 2)))
void lstm_k(
    const float* __restrict__ xin,   // [NSEQ][T_]
    const float* __restrict__ W_ih,  // [88]
    const float* __restrict__ W_hh,  // [88][22]
    const float* __restrict__ b_ih,  // [88]
    const float* __restrict__ b_hh,  // [88]
    _Float16* __restrict__ hsw)      // [B_][T_][22][22]
{
    __shared__ __align__(16) _Float16 hlds[SPW][36];  // h exchange (72B rows)
    __shared__ __align__(16) float    xlds[16][SPW];  // x stage [t_sub][m]

    const int lane = threadIdx.x;     // 0..63 (one wave per block)
    const int n = lane & 15;          // tile col / A-row / seq_local for stage
    const int g = lane >> 4;          // k-group / D-row group
    const int seg = blockIdx.x / NWQ;
    const int wq  = blockIdx.x - seg * NWQ;
    const int s0  = wq * SPW;

    // ---- resident weights: B fragments + per-tile wih/bias ----
    // tile tau: gate = tau>>1, hcol = (tau&1)*16 + n (valid < 22)
    f16x8_t bw[8];
    float wih_t[8], bias_t[8];
    #pragma unroll
    for (int tau = 0; tau < 8; ++tau) {
        const int gate = tau >> 1;
        const int hcol = ((tau & 1) << 4) + n;
        const bool vc = (hcol < H_);
        const int grow = gate * H_ + (vc ? hcol : 0);
        wih_t[tau]  = vc ? W_ih[grow] : 0.f;
        bias_t[tau] = vc ? (b_ih[grow] + b_hh[grow]) : 0.f;
        #pragma unroll
        for (int j = 0; j < 8; ++j) {
            const int k = (j < 4) ? (4 * g + j) : (16 + 4 * g + (j - 4));
            const float w = (vc && k < H_) ? W_hh[grow * H_ + k] : 0.f;
            bw[tau][j] = (_Float16)w;
        }
    }
    // pin: forbid remat/AGPR-parking of the resident weight set (R2 idiom)
    #pragma unroll
    for (int tau = 0; tau < 8; ++tau) {
        asm volatile("" : "+v"(bw[tau]));
        asm volatile("" : "+v"(wih_t[tau]), "+v"(bias_t[tau]));
    }

    // ---- zero h-exchange slab (all 36 cols), init c ----
    for (int i = lane; i < SPW * 36 / 2; i += 64)
        reinterpret_cast<unsigned int*>(&hlds[0][0])[i] = 0u;

    float c_st[2][4] = {{0.f, 0.f, 0.f, 0.f}, {0.f, 0.f, 0.f, 0.f}};

    const int t_s = seg * SEGLEN;
    const int t_e = t_s + SEGLEN;
    const int t_w = (seg == 0) ? 0 : (t_s - WARM);

    // ---- output pointers: one per r (half=1 is +16 elems = +32B imm) ----
    _Float16* hp[4];
    #pragma unroll
    for (int r = 0; r < 4; ++r) {
        const int sm = s0 + 4 * g + r;
        const int bb = sm / H_, cc = sm - bb * H_;
        hp[r] = hsw + ((size_t)bb * T_ + t_s) * 484 + cc * H_ + n;
    }

    auto run_chunk = [&](int tc, int tend, bool store_on) {
        // stage x[s0+n][tc..tc+15] -> xlds[t-tc][n] (clamped float4 loads;
        // duplicate clamped writes carry identical values -> benign)
        {
            int tb = tc + 4 * g;
            if (tb > T_ - 4) tb = T_ - 4;
            const float4 xv = *reinterpret_cast<const float4*>(
                xin + (size_t)(s0 + n) * T_ + tb);
            __builtin_amdgcn_wave_barrier();
            const int r0 = tb - tc;
            xlds[r0 + 0][n] = xv.x;
            xlds[r0 + 1][n] = xv.y;
            xlds[r0 + 2][n] = xv.z;
            xlds[r0 + 3][n] = xv.w;
            __builtin_amdgcn_wave_barrier();
        }
        for (int t4 = tc; t4 < tend; t4 += 4) {
            #pragma unroll
            for (int tt = 0; tt < 4; ++tt) {
                const int ts = t4 + tt - tc;
                __builtin_amdgcn_wave_barrier();
                // x for this lane's 4 D-rows (broadcast read, conflict-free)
                const f32x4_t xr =
                    *reinterpret_cast<const f32x4_t*>(&xlds[ts][4 * g]);
                // A fragment: row n, k = 4g+j and 16+4g+j
                const uint2 alo =
                    *reinterpret_cast<const uint2*>(&hlds[n][4 * g]);
                const uint2 ahi =
                    *reinterpret_cast<const uint2*>(&hlds[n][16 + 4 * g]);
                __builtin_amdgcn_wave_barrier();
                union { f16x8_t v; uint2 u2[2]; } au;
                au.u2[0] = alo; au.u2[1] = ahi;

                f32x4_t acc[8];
                #pragma unroll
                for (int tau = 0; tau < 8; ++tau) {
                    #pragma unroll
                    for (int r = 0; r < 4; ++r)
                        acc[tau][r] = fmaf(xr[r], wih_t[tau], bias_t[tau]);
                    acc[tau] = __builtin_amdgcn_mfma_f32_16x16x32_f16(
                        au.v, bw[tau], acc[tau], 0, 0, 0);
                }

                // activations + state; lane owns (m = 4g+r, hidx = 16*half+n)
                _Float16 h16[2][4];
                #pragma unroll
                for (int half = 0; half < 2; ++half) {
                    #pragma unroll
                    for (int r = 0; r < 4; ++r) {
                        const float ig = sigm(acc[0 + half][r]);
                        const float fg = sigm(acc[2 + half][r]);
                        const float gg = tanhfast(acc[4 + half][r]);
                        const float og = sigm(acc[6 + half][r]);
                        c_st[half][r] = fmaf(fg, c_st[half][r], ig * gg);
                        h16[half][r] = (_Float16)(og * tanhfast(c_st[half][r]));
                    }
                }
                // h feedback: cols 22..31 are a harmless dump (x0 weights)
                #pragma unroll
                for (int half = 0; half < 2; ++half) {
                    #pragma unroll
                    for (int r = 0; r < 4; ++r)
                        hlds[4 * g + r][(half << 4) + n] = h16[half][r];
                }
                __builtin_amdgcn_wave_barrier();

                if (store_on) {
                    #pragma unroll
                    for (int r = 0; r < 4; ++r) {
                        *reinterpret_cast<_Float16*>(
                            reinterpret_cast<char*>(hp[r]) + tt * 968) =
                            h16[0][r];
                        if (n < 6)
                            *reinterpret_cast<_Float16*>(
                                reinterpret_cast<char*>(hp[r]) + tt * 968 + 32) =
                                h16[1][r];
                    }
                }
            }
            if (store_on) {
                #pragma unroll
                for (int r = 0; r < 4; ++r)
                    hp[r] = reinterpret_cast<_Float16*>(
                        reinterpret_cast<char*>(hp[r]) + 4 * 968);
            }
        }
    };

    for (int tc = t_w; tc < t_s; tc += 16)
        run_chunk(tc, tc + 16, false);          // warm-up (t_s - t_w = 32)
    for (int tc = t_s; tc < t_e; tc += 16) {
        const int tend = (tc + 16 < t_e) ? (tc + 16) : t_e;
        run_chunk(tc, tend, true);              // stored segment
    }
}

// ---------------------------------------------------------------------------
// Kernel 2: conv(22ch, kh=22) + bias + ELU + BN(eval) + AvgPool(100).
// One block per (b, pool window p); 256 threads, 220 active: k = tid%22,
// t5 = tid/22 (0..9); each thread: 1 out-channel x 10 rows (t5 + 10i).
// fp16 hs + v_dot2_f32_f16: no unpack VALU, 2 MAC/op, fp32 accumulate.
// ---------------------------------------------------------------------------
__global__ __launch_bounds__(256) void conv_k(
    const _Float16* __restrict__ hsw,        // [B_][T_][22][22]
    const float* __restrict__ conv_w,        // [22][22][22]
    const float* __restrict__ conv_b,        // [22]
    const float* __restrict__ bn_g,
    const float* __restrict__ bn_b,
    const float* __restrict__ bn_m,
    const float* __restrict__ bn_v,
    float* __restrict__ pooled)              // [B_][22][10]
{
    __shared__ __align__(16) _Float16 wl[61 * 22 * 8];  // [cch][k][8]
    __shared__ __align__(16) _Float16 hl[40 * CSTR];
    __shared__ float pp[22 * TP];

    const int tid = threadIdx.x;
    const int b = blockIdx.x / TP;
    const int p = blockIdx.x - b * TP;

    if (tid < 22)
        *reinterpret_cast<uint2*>(&wl[(60 * 22 + tid) * 8 + 4]) = make_uint2(0u, 0u);
    for (int d = tid; d < 22 * 484; d += 256) {
        const float w = conv_w[d];
        const int k = d / 484, rem = d - k * 484;
        const int i2 = rem / 22, r = rem - i2 * 22;
        const int dp = r * 22 + i2;
        wl[((dp >> 3) * 22 + k) * 8 + (dp & 7)] = (_Float16)w;
    }

    const int k  = tid % 22;          // out channel
    const int t5 = tid / 22;          // row group (0..9 valid)
    const bool act = (tid < 220);

    const float cb = conv_b[k];
    const float mn = bn_m[k];
    const float bt = bn_b[k];
    const float inv = bn_g[k] * __frsqrt_rn(bn_v[k] + 1e-5f);

    float poolsum = 0.f;
    const _Float16* src = hsw + ((size_t)b * T_ + (size_t)p * POOL) * 484;
    const uint4* wl4 = reinterpret_cast<const uint4*>(wl);
    const uint4* hl4 = reinterpret_cast<const uint4*>(hl);

    for (int ph = 0; ph < 3; ++ph) {
        const int rows = (ph == 2) ? 20 : 40;
        const uint2* gsrc = reinterpret_cast<const uint2*>(src + (size_t)(ph * 40) * 484);
        const int n2 = rows * 121;
        for (int idx = tid; idx < n2; idx += 256) {
            const int tr = idx / 121, col = idx - tr * 121;
            reinterpret_cast<uint2*>(&hl[tr * CSTR])[col] = gsrc[idx];
        }
        for (int idx = tid; idx < rows; idx += 256)
            *reinterpret_cast<uint2*>(&hl[idx * CSTR + 484]) = make_uint2(0u, 0u);
        __syncthreads();

        if (act) {
            const int nrt = (ph == 2) ? 2 : 4;     // rows t5 + 10*i
            float acc[4] = {0.f, 0.f, 0.f, 0.f};
            for (int cch = 0; cch < 61; ++cch) {
                const uint4 wv = wl4[cch * 22 + k];
                const half2_t* w2 = reinterpret_cast<const half2_t*>(&wv);
                for (int i = 0; i < nrt; ++i) {
                    const uint4 hv = hl4[(t5 + 10 * i) * 61 + cch];
                    const half2_t* h2 = reinterpret_cast<const half2_t*>(&hv);
                    acc[i] = __builtin_amdgcn_fdot2(h2[0], w2[0], acc[i], false);
                    acc[i] = __builtin_amdgcn_fdot2(h2[1], w2[1], acc[i], false);
                    acc[i] = __builtin_amdgcn_fdot2(h2[2], w2[2], acc[i], false);
                    acc[i] = __builtin_amdgcn_fdot2(h2[3], w2[3], acc[i], false);
                }
            }
            const int nv = (ph == 2) ? 2 : 4;
            for (int i = 0; i < nv; ++i) {
                const float s = acc[i] + cb;
                const float e = (s > 0.f) ? s : (__expf(s) - 1.f);
                poolsum += fmaf(e - mn, inv, bt);
            }
        }
        __syncthreads();
    }

    if (act) pp[k * TP + t5] = poolsum;
    __syncthreads();
    if (tid < 22) {
        float s = 0.f;
        #pragma unroll
        for (int q = 0; q < TP; ++q) s += pp[tid * TP + q];
        pooled[((size_t)b * 22 + tid) * TP + p] = s * 0.01f;
    }
}

// ---------------------------------------------------------------------------
// Kernel 3: FC [64,220] x [220,4]^T + bias -> fp32 out. One thread per output.
// ---------------------------------------------------------------------------
__global__ __launch_bounds__(256) void fc_k(
    const float* __restrict__ pooled,  // [64][220] (idx = k*10+p)
    const float* __restrict__ fc_w,    // [4][220]
    const float* __restrict__ fc_b,    // [4]
    float* __restrict__ out)           // [64][4]
{
    const int tid = threadIdx.x;
    const int b = tid >> 2, n = tid & 3;
    const float* pv = pooled + b * 220;
    const float* wv = fc_w + n * 220;
    float s = fc_b[n];
    #pragma unroll 4
    for (int j = 0; j < 220; ++j)
        s = fmaf(pv[j], wv[j], s);
    out[tid] = s;
}

extern "C" void kernel_launch(void* const* d_in, const int* in_sizes, int n_in,
                              void* d_out, int out_size, void* d_ws, size_t ws_size,
                              hipStream_t stream) {
    const float* xin    = (const float*)d_in[0];
    const float* W_ih   = (const float*)d_in[1];
    const float* W_hh   = (const float*)d_in[2];
    const float* b_ih   = (const float*)d_in[3];
    const float* b_hh   = (const float*)d_in[4];
    const float* conv_w = (const float*)d_in[5];
    const float* conv_b = (const float*)d_in[6];
    const float* bn_g   = (const float*)d_in[7];
    const float* bn_b   = (const float*)d_in[8];
    const float* bn_m   = (const float*)d_in[9];
    const float* bn_v   = (const float*)d_in[10];
    const float* fc_w   = (const float*)d_in[11];
    const float* fc_b   = (const float*)d_in[12];

    _Float16* hsw = (_Float16*)d_ws;                                    // 61,952,000 B
    float* pooled = (float*)((char*)d_ws + (size_t)B_ * T_ * 484 * 2);  // 56,320 B

    lstm_k<<<NWQ * SEG, 64, 0, stream>>>(xin, W_ih, W_hh, b_ih, b_hh, hsw);
    conv_k<<<B_ * TP, 256, 0, stream>>>(hsw, conv_w, conv_b, bn_g, bn_b, bn_m, bn_v, pooled);
    fc_k<<<1, 256, 0, stream>>>(pooled, fc_w, fc_b, (float*)d_out);
}

// Round 4
// 295.471 us; speedup vs baseline: 1.2334x; 1.2334x over previous
//
#include <hip/hip_runtime.h>
#include <hip/hip_bf16.h>
#include <cstddef>

#define H_   22
#define T_   1000
#define B_   64
#define NSEQ (B_ * H_)      // 1408 sequences (B*C, C==22)
#define KP   22             // conv out channels
#define TP   10             // pooled time positions
#define POOL 100
#define CSTR 488            // conv hl row stride in fp16 (484 -> 488 = 61 uint4)
#define SEG  20             // temporal segments (R18: 10 -> 20 for occupancy)
#define WARM 32             // warm-up steps (R12-validated: fp16-floor exact)
#define SPW  16             // sequences per wave (MFMA M dimension)
#define NWQ  (NSEQ / SPW)   // 88 wave groups

typedef _Float16 half2_t  __attribute__((ext_vector_type(2)));
typedef _Float16 f16x8_t  __attribute__((ext_vector_type(8)));
typedef float    f32x4_t  __attribute__((ext_vector_type(4)));

#define LOG2E_F 1.44269504088896f

// Guaranteed-single-instruction transcendentals (R2-validated: -30% on lstm_k).
__device__ __forceinline__ float exp2_hw(float x) {
    float r; asm("v_exp_f32 %0, %1" : "=v"(r) : "v"(x)); return r;
}
__device__ __forceinline__ float rcp_hw(float x) {
    float r; asm("v_rcp_f32 %0, %1" : "=v"(r) : "v"(x)); return r;
}
// sigm: mul+exp+add+rcp (4 VALU); correct saturation at +/-inf.
__device__ __forceinline__ float sigm(float x) {
    return rcp_hw(1.f + exp2_hw(-LOG2E_F * x));
}
// tanh: mul+exp+add+rcp+fma (5 VALU); correct saturation.
__device__ __forceinline__ float tanhfast(float x) {
    return fmaf(-2.f, rcp_hw(1.f + exp2_hw((2.f * LOG2E_F) * x)), 1.f);
}

// ---------------------------------------------------------------------------
// Kernel 1 (R18): MFMA-batched independent LSTMs, occupancy-fixed.
// R3 post-mortem: structure correct (absmax at fp16 floor) and ~2x better
// per-seq issue cost than the scalar fdot2 version, but 880 single-wave
// blocks = 0.86 waves/SIMD => per-step serial chain (~3800 cyc: LDS
// round-trip + MFMA + 10 quarter-rate transcendentals) fully exposed.
// Fixes:
//  - SEG 10 -> 20 (1760 waves, 1.72/SIMD; steps/wave 132 -> ~82). 1000/20
//    is not 4-aligned (float4 x-staging needs tc%4==0), so segments are
//    MIXED: 10 segments of 52 + 10 of 48; all boundaries multiples of 4,
//    exact tiling of [0,1000), WARM=32 unchanged.
//  - acc pinned to VGPRs ("+v") before each MFMA: R3's VGPR_Count=92
//    suggests acc lived in AGPRs (64 v_accvgpr_* moves/step).
// Fragment layouts (guide-verified):
//   D/C: row = 4*(lane>>4)+reg, col = lane&15          [m89/m91]
//   A:   row = lane&15, k = 4*(lane>>4)+j (elems 0-3), +16 (elems 4-7)
//   B:   col = lane&15, same k mapping                  [m156/m162 tr-read]
// Zero discipline: B rows k>=22 and cols hcol>=22 zeroed in registers, so
// LDS cols 22..31 (activation dump) contribute 0; invalid preacts = 0.
// h exchange via per-wave LDS [16][36] fp16; x staged 16 steps at a time.
// ---------------------------------------------------------------------------
__global__ __launch_bounds__(64)
__attribute__((amdgpu_waves_per_eu(1, 2)))
void lstm_k(
    const float* __restrict__ xin,   // [NSEQ][T_]
    const float* __restrict__ W_ih,  // [88]
    const float* __restrict__ W_hh,  // [88][22]
    const float* __restrict__ b_ih,  // [88]
    const float* __restrict__ b_hh,  // [88]
    _Float16* __restrict__ hsw)      // [B_][T_][22][22]
{
    __shared__ __align__(16) _Float16 hlds[SPW][36];  // h exchange (72B rows)
    __shared__ __align__(16) float    xlds[16][SPW];  // x stage [t_sub][m]

    const int lane = threadIdx.x;     // 0..63 (one wave per block)
    const int n = lane & 15;          // tile col / A-row / seq_local for stage
    const int g = lane >> 4;          // k-group / D-row group
    const int seg = blockIdx.x / NWQ;
    const int wq  = blockIdx.x - seg * NWQ;
    const int s0  = wq * SPW;

    // ---- resident weights: B fragments + per-tile wih/bias ----
    // tile tau: gate = tau>>1, hcol = (tau&1)*16 + n (valid < 22)
    f16x8_t bw[8];
    float wih_t[8], bias_t[8];
    #pragma unroll
    for (int tau = 0; tau < 8; ++tau) {
        const int gate = tau >> 1;
        const int hcol = ((tau & 1) << 4) + n;
        const bool vc = (hcol < H_);
        const int grow = gate * H_ + (vc ? hcol : 0);
        wih_t[tau]  = vc ? W_ih[grow] : 0.f;
        bias_t[tau] = vc ? (b_ih[grow] + b_hh[grow]) : 0.f;
        #pragma unroll
        for (int j = 0; j < 8; ++j) {
            const int k = (j < 4) ? (4 * g + j) : (16 + 4 * g + (j - 4));
            const float w = (vc && k < H_) ? W_hh[grow * H_ + k] : 0.f;
            bw[tau][j] = (_Float16)w;
        }
    }
    // pin: forbid remat/AGPR-parking of the resident weight set (R2 idiom)
    #pragma unroll
    for (int tau = 0; tau < 8; ++tau) {
        asm volatile("" : "+v"(bw[tau]));
        asm volatile("" : "+v"(wih_t[tau]), "+v"(bias_t[tau]));
    }

    // ---- zero h-exchange slab (all 36 cols), init c ----
    for (int i = lane; i < SPW * 36 / 2; i += 64)
        reinterpret_cast<unsigned int*>(&hlds[0][0])[i] = 0u;

    float c_st[2][4] = {{0.f, 0.f, 0.f, 0.f}, {0.f, 0.f, 0.f, 0.f}};

    // mixed segment geometry: 10 x 52 then 10 x 48 (all 4-aligned)
    const int t_s = (seg < 10) ? 52 * seg : 520 + 48 * (seg - 10);
    const int t_e = t_s + ((seg < 10) ? 52 : 48);
    const int t_w = (seg == 0) ? 0 : (t_s - WARM);

    // ---- output pointers: one per r (half=1 is +16 elems = +32B imm) ----
    _Float16* hp[4];
    #pragma unroll
    for (int r = 0; r < 4; ++r) {
        const int sm = s0 + 4 * g + r;
        const int bb = sm / H_, cc = sm - bb * H_;
        hp[r] = hsw + ((size_t)bb * T_ + t_s) * 484 + cc * H_ + n;
    }

    auto run_chunk = [&](int tc, int tend, bool store_on) {
        // stage x[s0+n][tc..tc+15] -> xlds[t-tc][n] (clamped float4 loads;
        // duplicate clamped writes carry identical values -> benign)
        {
            int tb = tc + 4 * g;
            if (tb > T_ - 4) tb = T_ - 4;
            const float4 xv = *reinterpret_cast<const float4*>(
                xin + (size_t)(s0 + n) * T_ + tb);
            __builtin_amdgcn_wave_barrier();
            const int r0 = tb - tc;
            xlds[r0 + 0][n] = xv.x;
            xlds[r0 + 1][n] = xv.y;
            xlds[r0 + 2][n] = xv.z;
            xlds[r0 + 3][n] = xv.w;
            __builtin_amdgcn_wave_barrier();
        }
        for (int t4 = tc; t4 < tend; t4 += 4) {
            #pragma unroll
            for (int tt = 0; tt < 4; ++tt) {
                const int ts = t4 + tt - tc;
                __builtin_amdgcn_wave_barrier();
                // x for this lane's 4 D-rows (broadcast read, conflict-free)
                const f32x4_t xr =
                    *reinterpret_cast<const f32x4_t*>(&xlds[ts][4 * g]);
                // A fragment: row n, k = 4g+j and 16+4g+j
                const uint2 alo =
                    *reinterpret_cast<const uint2*>(&hlds[n][4 * g]);
                const uint2 ahi =
                    *reinterpret_cast<const uint2*>(&hlds[n][16 + 4 * g]);
                __builtin_amdgcn_wave_barrier();
                union { f16x8_t v; uint2 u2[2]; } au;
                au.u2[0] = alo; au.u2[1] = ahi;

                f32x4_t acc[8];
                #pragma unroll
                for (int tau = 0; tau < 8; ++tau) {
                    #pragma unroll
                    for (int r = 0; r < 4; ++r)
                        acc[tau][r] = fmaf(xr[r], wih_t[tau], bias_t[tau]);
                    // keep C in arch VGPRs (avoid accvgpr shuffling)
                    asm volatile("" : "+v"(acc[tau]));
                    acc[tau] = __builtin_amdgcn_mfma_f32_16x16x32_f16(
                        au.v, bw[tau], acc[tau], 0, 0, 0);
                }

                // activations + state; lane owns (m = 4g+r, hidx = 16*half+n)
                _Float16 h16[2][4];
                #pragma unroll
                for (int half = 0; half < 2; ++half) {
                    #pragma unroll
                    for (int r = 0; r < 4; ++r) {
                        const float ig = sigm(acc[0 + half][r]);
                        const float fg = sigm(acc[2 + half][r]);
                        const float gg = tanhfast(acc[4 + half][r]);
                        const float og = sigm(acc[6 + half][r]);
                        c_st[half][r] = fmaf(fg, c_st[half][r], ig * gg);
                        h16[half][r] = (_Float16)(og * tanhfast(c_st[half][r]));
                    }
                }
                // h feedback: cols 22..31 are a harmless dump (x0 weights)
                #pragma unroll
                for (int half = 0; half < 2; ++half) {
                    #pragma unroll
                    for (int r = 0; r < 4; ++r)
                        hlds[4 * g + r][(half << 4) + n] = h16[half][r];
                }
                __builtin_amdgcn_wave_barrier();

                if (store_on) {
                    #pragma unroll
                    for (int r = 0; r < 4; ++r) {
                        *reinterpret_cast<_Float16*>(
                            reinterpret_cast<char*>(hp[r]) + tt * 968) =
                            h16[0][r];
                        if (n < 6)
                            *reinterpret_cast<_Float16*>(
                                reinterpret_cast<char*>(hp[r]) + tt * 968 + 32) =
                                h16[1][r];
                    }
                }
            }
            if (store_on) {
                #pragma unroll
                for (int r = 0; r < 4; ++r)
                    hp[r] = reinterpret_cast<_Float16*>(
                        reinterpret_cast<char*>(hp[r]) + 4 * 968);
            }
        }
    };

    for (int tc = t_w; tc < t_s; tc += 16) {
        const int tend = (tc + 16 < t_s) ? (tc + 16) : t_s;
        run_chunk(tc, tend, false);             // warm-up (32 steps)
    }
    for (int tc = t_s; tc < t_e; tc += 16) {
        const int tend = (tc + 16 < t_e) ? (tc + 16) : t_e;
        run_chunk(tc, tend, true);              // stored segment (52 or 48)
    }
}

// ---------------------------------------------------------------------------
// Kernel 2: conv(22ch, kh=22) + bias + ELU + BN(eval) + AvgPool(100).
// One block per (b, pool window p); 256 threads, 220 active: k = tid%22,
// t5 = tid/22 (0..9); each thread: 1 out-channel x 10 rows (t5 + 10i).
// fp16 hs + v_dot2_f32_f16: no unpack VALU, 2 MAC/op, fp32 accumulate.
// ---------------------------------------------------------------------------
__global__ __launch_bounds__(256) void conv_k(
    const _Float16* __restrict__ hsw,        // [B_][T_][22][22]
    const float* __restrict__ conv_w,        // [22][22][22]
    const float* __restrict__ conv_b,        // [22]
    const float* __restrict__ bn_g,
    const float* __restrict__ bn_b,
    const float* __restrict__ bn_m,
    const float* __restrict__ bn_v,
    float* __restrict__ pooled)              // [B_][22][10]
{
    __shared__ __align__(16) _Float16 wl[61 * 22 * 8];  // [cch][k][8]
    __shared__ __align__(16) _Float16 hl[40 * CSTR];
    __shared__ float pp[22 * TP];

    const int tid = threadIdx.x;
    const int b = blockIdx.x / TP;
    const int p = blockIdx.x - b * TP;

    if (tid < 22)
        *reinterpret_cast<uint2*>(&wl[(60 * 22 + tid) * 8 + 4]) = make_uint2(0u, 0u);
    for (int d = tid; d < 22 * 484; d += 256) {
        const float w = conv_w[d];
        const int k = d / 484, rem = d - k * 484;
        const int i2 = rem / 22, r = rem - i2 * 22;
        const int dp = r * 22 + i2;
        wl[((dp >> 3) * 22 + k) * 8 + (dp & 7)] = (_Float16)w;
    }

    const int k  = tid % 22;          // out channel
    const int t5 = tid / 22;          // row group (0..9 valid)
    const bool act = (tid < 220);

    const float cb = conv_b[k];
    const float mn = bn_m[k];
    const float bt = bn_b[k];
    const float inv = bn_g[k] * __frsqrt_rn(bn_v[k] + 1e-5f);

    float poolsum = 0.f;
    const _Float16* src = hsw + ((size_t)b * T_ + (size_t)p * POOL) * 484;
    const uint4* wl4 = reinterpret_cast<const uint4*>(wl);
    const uint4* hl4 = reinterpret_cast<const uint4*>(hl);

    for (int ph = 0; ph < 3; ++ph) {
        const int rows = (ph == 2) ? 20 : 40;
        const uint2* gsrc = reinterpret_cast<const uint2*>(src + (size_t)(ph * 40) * 484);
        const int n2 = rows * 121;
        for (int idx = tid; idx < n2; idx += 256) {
            const int tr = idx / 121, col = idx - tr * 121;
            reinterpret_cast<uint2*>(&hl[tr * CSTR])[col] = gsrc[idx];
        }
        for (int idx = tid; idx < rows; idx += 256)
            *reinterpret_cast<uint2*>(&hl[idx * CSTR + 484]) = make_uint2(0u, 0u);
        __syncthreads();

        if (act) {
            const int nrt = (ph == 2) ? 2 : 4;     // rows t5 + 10*i
            float acc[4] = {0.f, 0.f, 0.f, 0.f};
            for (int cch = 0; cch < 61; ++cch) {
                const uint4 wv = wl4[cch * 22 + k];
                const half2_t* w2 = reinterpret_cast<const half2_t*>(&wv);
                for (int i = 0; i < nrt; ++i) {
                    const uint4 hv = hl4[(t5 + 10 * i) * 61 + cch];
                    const half2_t* h2 = reinterpret_cast<const half2_t*>(&hv);
                    acc[i] = __builtin_amdgcn_fdot2(h2[0], w2[0], acc[i], false);
                    acc[i] = __builtin_amdgcn_fdot2(h2[1], w2[1], acc[i], false);
                    acc[i] = __builtin_amdgcn_fdot2(h2[2], w2[2], acc[i], false);
                    acc[i] = __builtin_amdgcn_fdot2(h2[3], w2[3], acc[i], false);
                }
            }
            const int nv = (ph == 2) ? 2 : 4;
            for (int i = 0; i < nv; ++i) {
                const float s = acc[i] + cb;
                const float e = (s > 0.f) ? s : (__expf(s) - 1.f);
                poolsum += fmaf(e - mn, inv, bt);
            }
        }
        __syncthreads();
    }

    if (act) pp[k * TP + t5] = poolsum;
    __syncthreads();
    if (tid < 22) {
        float s = 0.f;
        #pragma unroll
        for (int q = 0; q < TP; ++q) s += pp[tid * TP + q];
        pooled[((size_t)b * 22 + tid) * TP + p] = s * 0.01f;
    }
}

// ---------------------------------------------------------------------------
// Kernel 3: FC [64,220] x [220,4]^T + bias -> fp32 out. One thread per output.
// ---------------------------------------------------------------------------
__global__ __launch_bounds__(256) void fc_k(
    const float* __restrict__ pooled,  // [64][220] (idx = k*10+p)
    const float* __restrict__ fc_w,    // [4][220]
    const float* __restrict__ fc_b,    // [4]
    float* __restrict__ out)           // [64][4]
{
    const int tid = threadIdx.x;
    const int b = tid >> 2, n = tid & 3;
    const float* pv = pooled + b * 220;
    const float* wv = fc_w + n * 220;
    float s = fc_b[n];
    #pragma unroll 4
    for (int j = 0; j < 220; ++j)
        s = fmaf(pv[j], wv[j], s);
    out[tid] = s;
}

extern "C" void kernel_launch(void* const* d_in, const int* in_sizes, int n_in,
                              void* d_out, int out_size, void* d_ws, size_t ws_size,
                              hipStream_t stream) {
    const float* xin    = (const float*)d_in[0];
    const float* W_ih   = (const float*)d_in[1];
    const float* W_hh   = (const float*)d_in[2];
    const float* b_ih   = (const float*)d_in[3];
    const float* b_hh   = (const float*)d_in[4];
    const float* conv_w = (const float*)d_in[5];
    const float* conv_b = (const float*)d_in[6];
    const float* bn_g   = (const float*)d_in[7];
    const float* bn_b   = (const float*)d_in[8];
    const float* bn_m   = (const float*)d_in[9];
    const float* bn_v   = (const float*)d_in[10];
    const float* fc_w   = (const float*)d_in[11];
    const float* fc_b   = (const float*)d_in[12];

    _Float16* hsw = (_Float16*)d_ws;                                    // 61,952,000 B
    float* pooled = (float*)((char*)d_ws + (size_t)B_ * T_ * 484 * 2);  // 56,320 B

    lstm_k<<<NWQ * SEG, 64, 0, stream>>>(xin, W_ih, W_hh, b_ih, b_hh, hsw);
    conv_k<<<B_ * TP, 256, 0, stream>>>(hsw, conv_w, conv_b, bn_g, bn_b, bn_m, bn_v, pooled);
    fc_k<<<1, 256, 0, stream>>>(pooled, fc_w, fc_b, (float*)d_out);
}